// Round 3
// baseline (332.740 us; speedup 1.0000x reference)
//
#include <hip/hip_runtime.h>

// B=256, L=8192, C=8. real: one-hot f32 [B,L,C]; pred: uniform f32 [B,L,C].
// Scalar f32 output: 0.5*(1-argmax_acc) + 0.5*(1-exactmatch_acc).
//
// Latency-bound fix (R1/R2): batch 8 independent float4 loads per thread BEFORE
// any compute (MLP), constant trip count, fused finalize via last-block ticket.

#define BLOCKS   4096
#define THREADS  256
#define NTHREADS (BLOCKS * THREADS)        // 1048576 threads
#define NPOS     (256 * 8192)              // 2097152 positions = 2 per thread

__device__ inline unsigned int pos_eval(float4 r0, float4 r1, float4 p0, float4 p1) {
    float r[8] = {r0.x, r0.y, r0.z, r0.w, r1.x, r1.y, r1.z, r1.w};
    float p[8] = {p0.x, p0.y, p0.z, p0.w, p1.x, p1.y, p1.z, p1.w};
    int   ta = 0, pa = 0;
    float tm = r[0], pm = p[0];
    bool  ex = true;
    #pragma unroll
    for (int k = 0; k < 8; ++k) {
        if (r[k] > tm) { tm = r[k]; ta = k; }   // first-occurrence argmax (strict >)
        if (p[k] > pm) { pm = p[k]; pa = k; }
        ex = ex && (r[k] == ((p[k] > 0.5f) ? 1.0f : 0.0f));  // real is exactly 0/1
    }
    return (unsigned int)(pa == ta) | ((unsigned int)ex << 16);
}

__global__ __launch_bounds__(THREADS) void ss_acc_loss_fused(
    const float* __restrict__ real,
    const float* __restrict__ pred,
    unsigned int* __restrict__ ws,   // ws[0]=argmax count, ws[1]=exact count, ws[2]=done ticket
    float* __restrict__ out)
{
    const int tid = blockIdx.x * THREADS + threadIdx.x;
    const float4* __restrict__ r4 = reinterpret_cast<const float4*>(real);
    const float4* __restrict__ p4 = reinterpret_cast<const float4*>(pred);

    // Two positions per thread, lane-interleaved for coalescing:
    //   position A = tid, position B = tid + NTHREADS.
    const size_t kA = 2 * (size_t)tid;
    const size_t kB = 2 * ((size_t)tid + (size_t)NTHREADS);

    // Issue all 8 loads up front -> 8 x 16B in flight per lane.
    float4 ra0 = r4[kA], ra1 = r4[kA + 1];
    float4 rb0 = r4[kB], rb1 = r4[kB + 1];
    float4 pa0 = p4[kA], pa1 = p4[kA + 1];
    float4 pb0 = p4[kB], pb1 = p4[kB + 1];

    unsigned int val = pos_eval(ra0, ra1, pa0, pa1)
                     + pos_eval(rb0, rb1, pb0, pb1);
    // val = c_arg | (c_exact<<16); per-block sums <= 512 per field, no overflow.

    #pragma unroll
    for (int off = 32; off > 0; off >>= 1)
        val += __shfl_down(val, off, 64);

    __shared__ unsigned int s[4];
    const int wave = threadIdx.x >> 6;
    const int lane = threadIdx.x & 63;
    if (lane == 0) s[wave] = val;
    __syncthreads();

    if (threadIdx.x == 0) {
        unsigned int tot = s[0] + s[1] + s[2] + s[3];
        atomicAdd(&ws[0], tot & 0xFFFFu);
        atomicAdd(&ws[1], tot >> 16);
        __threadfence();
        unsigned int done = atomicAdd(&ws[2], 1u);
        if (done == BLOCKS - 1) {
            // Last block: every other block's adds happened-before its ticket
            // increment (threadfence + device-scope atomics), so plain volatile
            // reads see the final sums.
            unsigned int c0 = ((volatile unsigned int*)ws)[0];
            unsigned int c1 = ((volatile unsigned int*)ws)[1];
            const float inv_n = 1.0f / (float)NPOS;   // 2^21 -> exact
            out[0] = 0.5f * (1.0f - (float)c0 * inv_n)
                   + 0.5f * (1.0f - (float)c1 * inv_n);
        }
    }
}

extern "C" void kernel_launch(void* const* d_in, const int* in_sizes, int n_in,
                              void* d_out, int out_size, void* d_ws, size_t ws_size,
                              hipStream_t stream) {
    const float* real = (const float*)d_in[0];
    const float* pred = (const float*)d_in[1];
    unsigned int* ws  = (unsigned int*)d_ws;
    float* out        = (float*)d_out;

    // ws is poisoned 0xAA before every launch -> zero counters + ticket.
    hipMemsetAsync(ws, 0, 3 * sizeof(unsigned int), stream);

    ss_acc_loss_fused<<<BLOCKS, THREADS, 0, stream>>>(real, pred, ws, out);
}

// Round 11
// 147.972 us; speedup vs baseline: 2.2487x; 2.2487x over previous
//
#include <hip/hip_runtime.h>

// B=256, L=8192, C=8. real: one-hot f32 [B,L,C]; pred: uniform f32 [B,L,C].
// Scalar f32 output: 0.5*(1-argmax_acc) + 0.5*(1-exactmatch_acc).
//
// R3..R10: R0's 66us == 4096 serialized device-scope atomics @ ~16ns (the
// whole runtime!); R2's 233us == 3.5x more of the same ops. Remove ALL
// atomics/fences/memset: per-block plain-store partials + tiny finalize
// kernel. Force MLP with an explicit 16-load cluster + sched_barrier(0)
// (R2's compiler serialized loads just-in-time, VGPR=24).

#define BLOCKS   2048
#define THREADS  256
#define S        (BLOCKS * THREADS)        // 524288 threads
#define NPOS     (256 * 8192)              // 2097152 positions = 4 per thread

__device__ __forceinline__ unsigned int pos_eval(float4 r0, float4 r1,
                                                 float4 p0, float4 p1) {
    float r[8] = {r0.x, r0.y, r0.z, r0.w, r1.x, r1.y, r1.z, r1.w};
    float p[8] = {p0.x, p0.y, p0.z, p0.w, p1.x, p1.y, p1.z, p1.w};
    int   ta = 0, pa = 0;
    float tm = r[0], pm = p[0];
    bool  ex = true;
    #pragma unroll
    for (int k = 0; k < 8; ++k) {
        if (r[k] > tm) { tm = r[k]; ta = k; }   // first-occurrence argmax (strict >)
        if (p[k] > pm) { pm = p[k]; pa = k; }
        ex = ex && (r[k] == ((p[k] > 0.5f) ? 1.0f : 0.0f));  // real is exactly 0/1
    }
    return (unsigned int)(pa == ta) | ((unsigned int)ex << 16);
}

__global__ __launch_bounds__(THREADS) void ss_acc_loss_main(
    const float* __restrict__ real,
    const float* __restrict__ pred,
    unsigned int* __restrict__ partial)   // [BLOCKS] packed: arg | exact<<16
{
    const int tid = blockIdx.x * THREADS + threadIdx.x;
    const float4* __restrict__ r4 = reinterpret_cast<const float4*>(real);
    const float4* __restrict__ p4 = reinterpret_cast<const float4*>(pred);

    // 4 positions per thread: tid + k*S (4 independent streams, lane stride 32B).
    const size_t k0 = 2 * (size_t)tid;
    const size_t k1 = k0 + 2 * (size_t)S;
    const size_t k2 = k1 + 2 * (size_t)S;
    const size_t k3 = k2 + 2 * (size_t)S;

    // Issue ALL 16 loads before any compute; sched_barrier(0) pins them.
    float4 ra0 = r4[k0], ra1 = r4[k0 + 1];
    float4 rb0 = r4[k1], rb1 = r4[k1 + 1];
    float4 rc0 = r4[k2], rc1 = r4[k2 + 1];
    float4 rd0 = r4[k3], rd1 = r4[k3 + 1];
    float4 pa0 = p4[k0], pa1 = p4[k0 + 1];
    float4 pb0 = p4[k1], pb1 = p4[k1 + 1];
    float4 pc0 = p4[k2], pc1 = p4[k2 + 1];
    float4 pd0 = p4[k3], pd1 = p4[k3 + 1];
    __builtin_amdgcn_sched_barrier(0);

    unsigned int val = pos_eval(ra0, ra1, pa0, pa1)
                     + pos_eval(rb0, rb1, pb0, pb1)
                     + pos_eval(rc0, rc1, pc0, pc1)
                     + pos_eval(rd0, rd1, pd0, pd1);
    // val = c_arg | (c_exact<<16); block sums <= 1024/field -> no overflow.

    #pragma unroll
    for (int off = 32; off > 0; off >>= 1)
        val += __shfl_down(val, off, 64);

    __shared__ unsigned int s[4];
    const int wave = threadIdx.x >> 6;
    const int lane = threadIdx.x & 63;
    if (lane == 0) s[wave] = val;
    __syncthreads();

    if (threadIdx.x == 0)
        partial[blockIdx.x] = s[0] + s[1] + s[2] + s[3];   // plain store, no atomics
}

__global__ __launch_bounds__(256) void ss_acc_loss_finalize(
    const unsigned int* __restrict__ partial,
    float* __restrict__ out)
{
    const int t = threadIdx.x;
    unsigned int a = 0, e = 0;
    #pragma unroll
    for (int j = 0; j < 8; ++j) {            // 2048 partials = 8 * 256, coalesced
        unsigned int v = partial[j * 256 + t];
        a += v & 0xFFFFu;
        e += v >> 16;
    }
    #pragma unroll
    for (int off = 32; off > 0; off >>= 1) {
        a += __shfl_down(a, off, 64);
        e += __shfl_down(e, off, 64);
    }
    __shared__ unsigned int sa[4], se[4];
    const int wave = t >> 6, lane = t & 63;
    if (lane == 0) { sa[wave] = a; se[wave] = e; }
    __syncthreads();
    if (t == 0) {
        unsigned int c0 = sa[0] + sa[1] + sa[2] + sa[3];
        unsigned int c1 = se[0] + se[1] + se[2] + se[3];
        const float inv_n = 1.0f / (float)NPOS;   // 2^21 -> exact
        out[0] = 0.5f * (1.0f - (float)c0 * inv_n)
               + 0.5f * (1.0f - (float)c1 * inv_n);
    }
}

extern "C" void kernel_launch(void* const* d_in, const int* in_sizes, int n_in,
                              void* d_out, int out_size, void* d_ws, size_t ws_size,
                              hipStream_t stream) {
    const float* real     = (const float*)d_in[0];
    const float* pred     = (const float*)d_in[1];
    unsigned int* partial = (unsigned int*)d_ws;   // fully overwritten, no init needed
    float* out            = (float*)d_out;

    ss_acc_loss_main<<<BLOCKS, THREADS, 0, stream>>>(real, pred, partial);
    ss_acc_loss_finalize<<<1, 256, 0, stream>>>(partial, out);
}

// Round 12
// 144.442 us; speedup vs baseline: 2.3036x; 1.0244x over previous
//
#include <hip/hip_runtime.h>

// B=256, L=8192, C=8. real: one-hot f32 [B,L,C]; pred: uniform f32 [B,L,C].
// Scalar f32 output: 0.5*(1-argmax_acc) + 0.5*(1-exactmatch_acc).
//
// R11: R3 confirmed atomic-tail theory (233 -> 45us main). VGPR=36 showed the
// compiler sustained only ~6 in-flight loads (burst-then-drain). Now: 8
// positions/thread, 4-slot software pipeline -- each consumed slot
// immediately re-issues its next loads, sustaining ~16 outstanding 1KB
// loads/wave. 1024 blocks = all co-resident (4 blocks/CU), no dispatch churn.

#define BLOCKS   1024
#define THREADS  256
#define S8       (BLOCKS * THREADS)        // 262144 threads
#define NPOS     (256 * 8192)              // 2097152 = 8 * S8 positions

__device__ __forceinline__ unsigned int pos_eval(float4 r0, float4 r1,
                                                 float4 p0, float4 p1) {
    float r[8] = {r0.x, r0.y, r0.z, r0.w, r1.x, r1.y, r1.z, r1.w};
    float p[8] = {p0.x, p0.y, p0.z, p0.w, p1.x, p1.y, p1.z, p1.w};
    int   ta = 0, pa = 0;
    float tm = r[0], pm = p[0];
    bool  ex = true;
    #pragma unroll
    for (int k = 0; k < 8; ++k) {
        if (r[k] > tm) { tm = r[k]; ta = k; }   // first-occurrence argmax (strict >)
        if (p[k] > pm) { pm = p[k]; pa = k; }
        ex = ex && (r[k] == ((p[k] > 0.5f) ? 1.0f : 0.0f));  // real is exactly 0/1
    }
    return (unsigned int)(pa == ta) | ((unsigned int)ex << 16);
}

__global__ __launch_bounds__(THREADS) void ss_acc_loss_main(
    const float* __restrict__ real,
    const float* __restrict__ pred,
    unsigned int* __restrict__ partial)   // [BLOCKS] packed: arg | exact<<16
{
    const int tid = blockIdx.x * THREADS + threadIdx.x;
    const float4* __restrict__ r4 = reinterpret_cast<const float4*>(real);
    const float4* __restrict__ p4 = reinterpret_cast<const float4*>(pred);

    float4 ra0, ra1, qa0, qa1;   // slot a
    float4 rb0, rb1, qb0, qb1;   // slot b
    float4 rc0, rc1, qc0, qc1;   // slot c
    float4 rd0, rd1, qd0, qd1;   // slot d

    // ISSUE(slot, j): load position (tid + j*S8) into the slot's 4 float4s.
#define ISSUE(s, j) do {                                              \
        size_t k_ = 2 * ((size_t)tid + (size_t)(j) * S8);             \
        r##s##0 = r4[k_];  r##s##1 = r4[k_ + 1];                      \
        q##s##0 = p4[k_];  q##s##1 = p4[k_ + 1];                      \
    } while (0)

    // Prologue: fill all 4 slots (16 loads in flight).
    ISSUE(a, 0); ISSUE(b, 1); ISSUE(c, 2); ISSUE(d, 3);

    // Steady state: consume a slot, immediately refill it (WAR renamed by
    // compiler, so the refill issues without waiting on the eval).
    unsigned int val;
    val  = pos_eval(ra0, ra1, qa0, qa1);  ISSUE(a, 4);
    val += pos_eval(rb0, rb1, qb0, qb1);  ISSUE(b, 5);
    val += pos_eval(rc0, rc1, qc0, qc1);  ISSUE(c, 6);
    val += pos_eval(rd0, rd1, qd0, qd1);  ISSUE(d, 7);
    // Epilogue: drain.
    val += pos_eval(ra0, ra1, qa0, qa1);
    val += pos_eval(rb0, rb1, qb0, qb1);
    val += pos_eval(rc0, rc1, qc0, qc1);
    val += pos_eval(rd0, rd1, qd0, qd1);
#undef ISSUE
    // val = c_arg | (c_exact<<16); block sums <= 2048/field -> no overflow.

    #pragma unroll
    for (int off = 32; off > 0; off >>= 1)
        val += __shfl_down(val, off, 64);

    __shared__ unsigned int s[4];
    const int wave = threadIdx.x >> 6;
    const int lane = threadIdx.x & 63;
    if (lane == 0) s[wave] = val;
    __syncthreads();

    if (threadIdx.x == 0)
        partial[blockIdx.x] = s[0] + s[1] + s[2] + s[3];   // plain store, no atomics
}

__global__ __launch_bounds__(256) void ss_acc_loss_finalize(
    const unsigned int* __restrict__ partial,
    float* __restrict__ out)
{
    const int t = threadIdx.x;
    unsigned int a = 0, e = 0;
    #pragma unroll
    for (int j = 0; j < 4; ++j) {            // 1024 partials = 4 * 256, coalesced
        unsigned int v = partial[j * 256 + t];
        a += v & 0xFFFFu;
        e += v >> 16;
    }
    #pragma unroll
    for (int off = 32; off > 0; off >>= 1) {
        a += __shfl_down(a, off, 64);
        e += __shfl_down(e, off, 64);
    }
    __shared__ unsigned int sa[4], se[4];
    const int wave = t >> 6, lane = t & 63;
    if (lane == 0) { sa[wave] = a; se[wave] = e; }
    __syncthreads();
    if (t == 0) {
        unsigned int c0 = sa[0] + sa[1] + sa[2] + sa[3];
        unsigned int c1 = se[0] + se[1] + se[2] + se[3];
        const float inv_n = 1.0f / (float)NPOS;   // 2^21 -> exact
        out[0] = 0.5f * (1.0f - (float)c0 * inv_n)
               + 0.5f * (1.0f - (float)c1 * inv_n);
    }
}

extern "C" void kernel_launch(void* const* d_in, const int* in_sizes, int n_in,
                              void* d_out, int out_size, void* d_ws, size_t ws_size,
                              hipStream_t stream) {
    const float* real     = (const float*)d_in[0];
    const float* pred     = (const float*)d_in[1];
    unsigned int* partial = (unsigned int*)d_ws;   // fully overwritten, no init needed
    float* out            = (float*)d_out;

    ss_acc_loss_main<<<BLOCKS, THREADS, 0, stream>>>(real, pred, partial);
    ss_acc_loss_finalize<<<1, 256, 0, stream>>>(partial, out);
}

// Round 15
// 141.397 us; speedup vs baseline: 2.3532x; 1.0215x over previous
//
#include <hip/hip_runtime.h>

// B=256, L=8192, C=8. real: one-hot f32 [B,L,C]; pred: uniform f32 [B,L,C].
// Scalar f32 output: 0.5*(1-argmax_acc) + 0.5*(1-exactmatch_acc).
//
// R14/R15 (= R13 with LDS geometry fixed under the 64KB/workgroup cap):
// R3/R12 both pinned at ~45us, ~3TB/s effective; compiler caps VGPR in-flight
// loads at ~6/wave (VGPR=36/40). Bypass the register file: global_load_lds
// DMA (no VGPR dest, vmcnt-queued) stages each block's 32KB chunk into LDS;
// compute reads LDS dense (float4/lane = half-position), pair lanes combine
// via 3x shfl_xor. Both pair-lanes count each position -> finalize divides
// by 2*NPOS.

#define BLOCKS   4096
#define THREADS  256
#define NPOS     (256 * 8192)          // 2097152 positions = 512/block
#define F4_PER_ARRAY 1024              // 512 positions * 2 float4, per array

__device__ __forceinline__ void async_copy16(const float4* g, void* l) {
    __builtin_amdgcn_global_load_lds(
        (const __attribute__((address_space(1))) void*)g,
        (__attribute__((address_space(3))) void*)l,
        16, 0, 0);   // 16B per lane; LDS dest = wave-uniform base + lane*16
}

__global__ __launch_bounds__(THREADS) void ss_acc_loss_main(
    const float* __restrict__ real,
    const float* __restrict__ pred,
    unsigned int* __restrict__ partial)   // [BLOCKS] packed: arg | exact<<16
{
    extern __shared__ float4 smem[];          // [0,1024) = real, [1024,2048) = pred
    float4* lds_r = smem;
    float4* lds_p = smem + F4_PER_ARRAY;

    const float4* __restrict__ r4 = reinterpret_cast<const float4*>(real);
    const float4* __restrict__ p4 = reinterpret_cast<const float4*>(pred);

    const int t    = threadIdx.x;
    const int w    = t >> 6;                  // wave 0..3
    const int lane = t & 63;

    // ---- Stage 32KB (16KB real + 16KB pred) via global_load_lds ----
    // Wave w covers float4 indices [w*256, (w+1)*256) of this block's chunk.
    const size_t base = (size_t)blockIdx.x * F4_PER_ARRAY + (size_t)w * 256 + lane;
    const float4* gr = r4 + base;
    const float4* gp = p4 + base;
    char* lr = (char*)&lds_r[w * 256];        // wave-uniform LDS bases
    char* lp = (char*)&lds_p[w * 256];
    #pragma unroll
    for (int j = 0; j < 4; ++j) {             // 8 x 1KB DMAs in flight per wave
        async_copy16(gr + j * 64, lr + j * 1024);
        async_copy16(gp + j * 64, lp + j * 1024);
    }
    __syncthreads();                          // drains vmcnt(0) + barrier

    // ---- Compute: dense float4 per lane = half a position ----
    unsigned int val = 0;
    const bool odd = t & 1;
    #pragma unroll
    for (int j = 0; j < 4; ++j) {
        const int idx = j * 256 + t;          // 0..1023, lane-dense
        float4 r = lds_r[idx];
        float4 p = lds_p[idx];

        // local argmax over this half's 4 classes (strict > = first occurrence)
        int la = 0; float lm = r.x;
        if (r.y > lm) { lm = r.y; la = 1; }
        if (r.z > lm) { lm = r.z; la = 2; }
        if (r.w > lm) { lm = r.w; la = 3; }
        int qa = 0; float qm = p.x;
        if (p.y > qm) { qm = p.y; qa = 1; }
        if (p.z > qm) { qm = p.z; qa = 2; }
        if (p.w > qm) { qm = p.w; qa = 3; }
        bool ex = (r.x == ((p.x > 0.5f) ? 1.0f : 0.0f)) &
                  (r.y == ((p.y > 0.5f) ? 1.0f : 0.0f)) &
                  (r.z == ((p.z > 0.5f) ? 1.0f : 0.0f)) &
                  (r.w == ((p.w > 0.5f) ? 1.0f : 0.0f));
        unsigned meta = (unsigned)la | ((unsigned)qa << 4) | ((unsigned)ex << 8);

        // combine with pair lane (t^1): even lane = classes 0-3, odd = 4-7
        float lm_o = __shfl_xor(lm, 1, 64);
        float qm_o = __shfl_xor(qm, 1, 64);
        unsigned mo = __shfl_xor(meta, 1, 64);
        float tmL = odd ? lm_o : lm,  tmH = odd ? lm : lm_o;
        float pmL = odd ? qm_o : qm,  pmH = odd ? qm : qm_o;
        unsigned mL = odd ? mo : meta, mH = odd ? meta : mo;

        // across halves: high wins only on strictly greater (ties -> low idx)
        int ta = (tmH > tmL) ? (int)(mH & 15u) + 4 : (int)(mL & 15u);
        int pa = (pmH > pmL) ? (int)((mH >> 4) & 15u) + 4 : (int)((mL >> 4) & 15u);
        unsigned exg = ((mL & mH) >> 8) & 1u;
        val += (unsigned)(ta == pa) | (exg << 16);
    }
    // Each position counted by BOTH pair lanes; block sum <= 1024/field.

    #pragma unroll
    for (int off = 32; off > 0; off >>= 1)
        val += __shfl_down(val, off, 64);

    __shared__ unsigned int sred[4];
    if (lane == 0) sred[w] = val;
    __syncthreads();

    if (t == 0)
        partial[blockIdx.x] = sred[0] + sred[1] + sred[2] + sred[3];  // plain store
}

__global__ __launch_bounds__(256) void ss_acc_loss_finalize(
    const unsigned int* __restrict__ partial,
    float* __restrict__ out)
{
    const int t = threadIdx.x;
    unsigned int a = 0, e = 0;
    #pragma unroll
    for (int j = 0; j < 16; ++j) {           // 4096 partials = 16 * 256, coalesced
        unsigned int v = partial[j * 256 + t];
        a += v & 0xFFFFu;
        e += v >> 16;
    }
    #pragma unroll
    for (int off = 32; off > 0; off >>= 1) {
        a += __shfl_down(a, off, 64);
        e += __shfl_down(e, off, 64);
    }
    __shared__ unsigned int sa[4], se[4];
    const int wave = t >> 6, lane = t & 63;
    if (lane == 0) { sa[wave] = a; se[wave] = e; }
    __syncthreads();
    if (t == 0) {
        unsigned int c0 = sa[0] + sa[1] + sa[2] + sa[3];   // double-counted
        unsigned int c1 = se[0] + se[1] + se[2] + se[3];
        const float inv_n = 1.0f / (float)(2 * NPOS);      // 2^22 -> exact
        out[0] = 0.5f * (1.0f - (float)c0 * inv_n)
               + 0.5f * (1.0f - (float)c1 * inv_n);
    }
}

extern "C" void kernel_launch(void* const* d_in, const int* in_sizes, int n_in,
                              void* d_out, int out_size, void* d_ws, size_t ws_size,
                              hipStream_t stream) {
    const float* real     = (const float*)d_in[0];
    const float* pred     = (const float*)d_in[1];
    unsigned int* partial = (unsigned int*)d_ws;   // fully overwritten, no init needed
    float* out            = (float*)d_out;

    ss_acc_loss_main<<<BLOCKS, THREADS, 32768, stream>>>(real, pred, partial);
    ss_acc_loss_finalize<<<1, 256, 0, stream>>>(partial, out);
}